// Round 1
// baseline (64.436 us; speedup 1.0000x reference)
//
#include <hip/hip_runtime.h>

#define THREADS 512
#define NROW 65536
#define NBINS 8192
#define SEG (NBINS / THREADS)   // 16 bins per thread
#define CAND_CAP 4096
#define KP1 656                 // K+1, K = int(0.01*(65536-1)) = 655
#define TEMP 10.0f

// order-preserving float -> uint key (larger key == larger float)
__device__ __forceinline__ unsigned f2key(float f) {
    unsigned u = __float_as_uint(f);
    return (u & 0x80000000u) ? ~u : (u | 0x80000000u);
}
__device__ __forceinline__ float key2f(unsigned k) {
    unsigned u = (k & 0x80000000u) ? (k & 0x7FFFFFFFu) : ~k;
    return __uint_as_float(u);
}

__global__ __launch_bounds__(THREADS)
void mmcl_row_kernel(const float* __restrict__ logits,
                     const int* __restrict__ targets,
                     float* __restrict__ row_loss) {
    const int row = blockIdx.x;
    const int tid = threadIdx.x;
    const float* rowp = logits + (size_t)row * NROW;

    __shared__ unsigned hist[NBINS];
    __shared__ unsigned cand[CAND_CAP];
    __shared__ unsigned sscan[THREADS];
    __shared__ unsigned s_maxkey;
    __shared__ int s_b, s_r, s_cnum;
    __shared__ float s_t;
    __shared__ float s_red[THREADS / 64];

    for (int i = tid; i < NBINS; i += THREADS) hist[i] = 0u;
    if (tid == 0) {
        s_maxkey = 0u;
        s_cnum = 0;
        s_t = rowp[targets[row]];
    }
    __syncthreads();

    // ---------- Pass A: histogram of top 13 key bits + exact max ----------
    const float4* rp4 = (const float4*)rowp;
    unsigned lmax = 0u;
    for (int i = tid; i < NROW / 4; i += THREADS) {
        float4 v = rp4[i];
        unsigned k0 = f2key(v.x), k1 = f2key(v.y), k2 = f2key(v.z), k3 = f2key(v.w);
        lmax = max(max(lmax, k0), max(k1, max(k2, k3)));
        atomicAdd(&hist[k0 >> 19], 1u);
        atomicAdd(&hist[k1 >> 19], 1u);
        atomicAdd(&hist[k2 >> 19], 1u);
        atomicAdd(&hist[k3 >> 19], 1u);
    }
    // wave max then one shared atomic per wave
    for (int off = 32; off > 0; off >>= 1) {
        unsigned o = (unsigned)__shfl_down((int)lmax, off);
        lmax = max(lmax, o);
    }
    if ((tid & 63) == 0) atomicMax(&s_maxkey, lmax);
    __syncthreads();

    // ---------- find boundary bin b and rank r via suffix scan ----------
    unsigned seg = 0u;
    #pragma unroll
    for (int j = 0; j < SEG; ++j) seg += hist[tid * SEG + j];
    sscan[tid] = seg;
    __syncthreads();
    for (int off = 1; off < THREADS; off <<= 1) {
        unsigned t2 = (tid + off < THREADS) ? sscan[tid + off] : 0u;
        __syncthreads();
        sscan[tid] += t2;
        __syncthreads();
    }
    // sscan[tid] = F(tid*SEG) = count of values in bins >= tid*SEG
    {
        unsigned Fme = sscan[tid];
        unsigned Fnx = (tid + 1 < THREADS) ? sscan[tid + 1] : 0u;
        if (Fme >= KP1 && Fnx < KP1) {          // crossing lies in my segment
            unsigned g = Fnx;                    // count strictly above current bin
            for (int bin = tid * SEG + SEG - 1; bin >= tid * SEG; --bin) {
                unsigned h = hist[bin];
                if (g + h >= KP1) { s_b = bin; s_r = KP1 - (int)g; break; }
                g += h;
            }
        }
    }
    __syncthreads();

    const unsigned b = (unsigned)s_b;
    const float m = key2f(s_maxkey);

    // ---------- Pass B: accumulate exp for bins > b, gather bin == b ----------
    float lsum = 0.0f;
    for (int i = tid; i < NROW / 4; i += THREADS) {
        float4 v = rp4[i];
        float vv[4] = {v.x, v.y, v.z, v.w};
        #pragma unroll
        for (int c = 0; c < 4; ++c) {
            unsigned k = f2key(vv[c]);
            unsigned bin = k >> 19;
            if (bin > b) {
                lsum += expf(TEMP * (vv[c] - m));
            } else if (bin == b) {
                int idx = atomicAdd(&s_cnum, 1);
                if (idx < CAND_CAP) cand[idx] = k;
            }
        }
    }
    __syncthreads();

    // ---------- bitonic sort candidates (descending by key) ----------
    int C = s_cnum; if (C > CAND_CAP) C = CAND_CAP;
    int P = 2; while (P < C) P <<= 1;
    for (int i = C + tid; i < P; i += THREADS) cand[i] = 0u;  // pad = smallest key
    __syncthreads();
    for (int kk = 2; kk <= P; kk <<= 1) {
        for (int j = kk >> 1; j > 0; j >>= 1) {
            for (int i = tid; i < P; i += THREADS) {
                int ixj = i ^ j;
                if (ixj > i) {
                    unsigned a = cand[i], c2 = cand[ixj];
                    bool sw = ((i & kk) == 0) ? (a < c2) : (a > c2); // descending
                    if (sw) { cand[i] = c2; cand[ixj] = a; }
                }
            }
            __syncthreads();
        }
    }

    // ---------- top-r candidates + final per-row loss ----------
    const int r = s_r;
    float csum = 0.0f;
    for (int i = tid; i < r; i += THREADS)
        csum += expf(TEMP * (key2f(cand[i]) - m));

    float tot = lsum + csum;
    for (int off = 32; off > 0; off >>= 1) tot += __shfl_down(tot, off);
    if ((tid & 63) == 0) s_red[tid >> 6] = tot;
    __syncthreads();
    if (tid == 0) {
        float sum656 = 0.0f;
        #pragma unroll
        for (int w = 0; w < THREADS / 64; ++w) sum656 += s_red[w];
        float v656 = key2f(cand[r - 1]);   // 656-th largest value in the row
        float t = s_t;
        float ps;
        if (t >= v656) {
            // target inside top-656 (or tied): candidate multiset == S
            ps = TEMP * m + logf(sum656) - TEMP * t;
        } else {
            // candidate multiset == top-655 + {t}
            ps = TEMP * m + logf(sum656 - expf(TEMP * (v656 - m)) + expf(TEMP * (t - m)))
                 - TEMP * t;
        }
        row_loss[row] = ps;
    }
}

__global__ __launch_bounds__(512)
void mmcl_reduce_kernel(const float* __restrict__ row_loss, float* __restrict__ out) {
    __shared__ float s_red[8];
    int tid = threadIdx.x;
    float v = row_loss[tid];
    for (int off = 32; off > 0; off >>= 1) v += __shfl_down(v, off);
    if ((tid & 63) == 0) s_red[tid >> 6] = v;
    __syncthreads();
    if (tid == 0) {
        float s = 0.0f;
        #pragma unroll
        for (int w = 0; w < 8; ++w) s += s_red[w];
        out[0] = s / 512.0f;
    }
}

extern "C" void kernel_launch(void* const* d_in, const int* in_sizes, int n_in,
                              void* d_out, int out_size, void* d_ws, size_t ws_size,
                              hipStream_t stream) {
    const float* logits = (const float*)d_in[0];   // [512, 65536] f32
    const int* targets = (const int*)d_in[1];      // [512] i32
    float* out = (float*)d_out;                    // scalar f32
    float* ws = (float*)d_ws;                      // >= 512 floats

    mmcl_row_kernel<<<512, THREADS, 0, stream>>>(logits, targets, ws);
    mmcl_reduce_kernel<<<1, 512, 0, stream>>>(ws, out);
}

// Round 2
// 50.360 us; speedup vs baseline: 1.2795x; 1.2795x over previous
//
#include <hip/hip_runtime.h>

#define THREADS 512
#define NROW 65536
#define NBINS 8192
#define SEG (NBINS / THREADS)   // 16 bins per thread
#define CAND_CAP 4096           // survivor buffer
#define CAP2 2048               // boundary-bin candidate buffer
#define KP1 656                 // K+1, K = int(0.01*(65536-1)) = 655
#define SMARGIN 80u             // sample suffix-count threshold (+6 sigma vs 41)
#define TEMP 10.0f

// order-preserving float -> uint key (larger key == larger float)
__device__ __forceinline__ unsigned f2key(float f) {
    unsigned u = __float_as_uint(f);
    return (u & 0x80000000u) ? ~u : (u | 0x80000000u);
}
__device__ __forceinline__ float key2f(unsigned k) {
    unsigned u = (k & 0x80000000u) ? (k & 0x7FFFFFFFu) : ~k;
    return __uint_as_float(u);
}

// Suffix-scan hist[NBINS]; find smallest bin b with sum(hist[b..]) >= thresh,
// and r = thresh - sum(hist[b+1..]). Requires barrier-synced entry; ends synced.
__device__ void suffix_find(unsigned* hist, unsigned* sscan, int tid,
                            unsigned thresh, int* s_b, int* s_r) {
    unsigned seg = 0u;
    #pragma unroll
    for (int j = 0; j < SEG; ++j) seg += hist[tid * SEG + j];
    sscan[tid] = seg;
    __syncthreads();
    for (int off = 1; off < THREADS; off <<= 1) {
        unsigned t2 = (tid + off < THREADS) ? sscan[tid + off] : 0u;
        __syncthreads();
        sscan[tid] += t2;
        __syncthreads();
    }
    unsigned Fme = sscan[tid];
    unsigned Fnx = (tid + 1 < THREADS) ? sscan[tid + 1] : 0u;
    if (Fme >= thresh && Fnx < thresh) {
        unsigned g = Fnx;  // count strictly above current bin
        for (int bin = tid * SEG + SEG - 1; bin >= tid * SEG; --bin) {
            unsigned h = hist[bin];
            if (g + h >= thresh) { *s_b = bin; *s_r = (int)(thresh - g); break; }
            g += h;
        }
    }
    __syncthreads();
}

__global__ __launch_bounds__(THREADS)
void mmcl_row_kernel(const float* __restrict__ logits,
                     const int* __restrict__ targets,
                     float* __restrict__ row_loss) {
    const int row = blockIdx.x;
    const int tid = threadIdx.x;
    const float* rowp = logits + (size_t)row * NROW;
    const float4* rp4 = (const float4*)rowp;

    __shared__ unsigned hist[NBINS];
    __shared__ unsigned cand[CAND_CAP];   // survivor keys
    __shared__ unsigned cand2[CAP2];      // boundary-bin keys
    __shared__ unsigned sscan[THREADS];
    __shared__ unsigned s_maxkey;
    __shared__ int s_bs, s_rs, s_b, s_r, s_cnum, s_c2num;
    __shared__ float s_t;
    __shared__ float s_red[THREADS / 64];

    for (int i = tid; i < NBINS; i += THREADS) hist[i] = 0u;
    if (tid == 0) {
        s_maxkey = 0u;
        s_cnum = 0;
        s_c2num = 0;
        s_t = rowp[targets[row]];
    }
    __syncthreads();

    // ---------- Phase 1: histogram a 4096-element sample -> threshold bin bs --
    for (int i = tid; i < 1024; i += THREADS) {      // first 4096 floats of row
        float4 v = rp4[i];
        atomicAdd(&hist[f2key(v.x) >> 19], 1u);
        atomicAdd(&hist[f2key(v.y) >> 19], 1u);
        atomicAdd(&hist[f2key(v.z) >> 19], 1u);
        atomicAdd(&hist[f2key(v.w) >> 19], 1u);
    }
    __syncthreads();
    suffix_find(hist, sscan, tid, SMARGIN, &s_bs, &s_rs);
    const unsigned bs = (unsigned)s_bs;
    // clear hist for reuse (completes before next hist use: barrier after stream)
    for (int i = tid; i < NBINS; i += THREADS) hist[i] = 0u;

    // ---------- Phase 2: single full stream: row max + filter survivors ------
    unsigned lmax = 0u;
    #pragma unroll 4
    for (int i = tid; i < NROW / 4; i += THREADS) {
        float4 v = rp4[i];
        unsigned k0 = f2key(v.x), k1 = f2key(v.y), k2 = f2key(v.z), k3 = f2key(v.w);
        lmax = max(max(lmax, k0), max(k1, max(k2, k3)));
        if ((k0 >> 19) >= bs) { int ix = atomicAdd(&s_cnum, 1); if (ix < CAND_CAP) cand[ix] = k0; }
        if ((k1 >> 19) >= bs) { int ix = atomicAdd(&s_cnum, 1); if (ix < CAND_CAP) cand[ix] = k1; }
        if ((k2 >> 19) >= bs) { int ix = atomicAdd(&s_cnum, 1); if (ix < CAND_CAP) cand[ix] = k2; }
        if ((k3 >> 19) >= bs) { int ix = atomicAdd(&s_cnum, 1); if (ix < CAND_CAP) cand[ix] = k3; }
    }
    for (int off = 32; off > 0; off >>= 1) {
        unsigned o = (unsigned)__shfl_down((int)lmax, off);
        lmax = max(lmax, o);
    }
    if ((tid & 63) == 0) atomicMax(&s_maxkey, lmax);
    __syncthreads();

    const float m = key2f(s_maxkey);
    const int C = s_cnum;
    const bool fast = (C >= KP1 && C <= CAND_CAP);

    float lsum = 0.0f;  // exp-sum of values in bins strictly above boundary bin

    if (fast) {
        // exact selection among the C survivors (superset of top-656)
        for (int i = tid; i < C; i += THREADS) atomicAdd(&hist[cand[i] >> 19], 1u);
        __syncthreads();
        suffix_find(hist, sscan, tid, KP1, &s_b, &s_r);
        const unsigned b = (unsigned)s_b;
        for (int i = tid; i < C; i += THREADS) {
            unsigned k = cand[i];
            unsigned bin = k >> 19;
            if (bin > b) {
                lsum += expf(TEMP * (key2f(k) - m));
            } else if (bin == b) {
                int ix = atomicAdd(&s_c2num, 1);
                if (ix < CAP2) cand2[ix] = k;
            }
        }
        __syncthreads();
    } else {
        // ---- exact fallback: full histogram over the row (never taken for
        // well-behaved inputs; guarantees correctness regardless of data) ----
        for (int i = tid; i < NROW / 4; i += THREADS) {
            float4 v = rp4[i];
            atomicAdd(&hist[f2key(v.x) >> 19], 1u);
            atomicAdd(&hist[f2key(v.y) >> 19], 1u);
            atomicAdd(&hist[f2key(v.z) >> 19], 1u);
            atomicAdd(&hist[f2key(v.w) >> 19], 1u);
        }
        __syncthreads();
        suffix_find(hist, sscan, tid, KP1, &s_b, &s_r);
        const unsigned b = (unsigned)s_b;
        for (int i = tid; i < NROW / 4; i += THREADS) {
            float4 v = rp4[i];
            float vv[4] = {v.x, v.y, v.z, v.w};
            #pragma unroll
            for (int c = 0; c < 4; ++c) {
                unsigned k = f2key(vv[c]);
                unsigned bin = k >> 19;
                if (bin > b) {
                    lsum += expf(TEMP * (vv[c] - m));
                } else if (bin == b) {
                    int ix = atomicAdd(&s_c2num, 1);
                    if (ix < CAP2) cand2[ix] = k;
                }
            }
        }
        __syncthreads();
    }

    // ---------- bitonic sort boundary-bin candidates (descending) ------------
    int C2 = s_c2num; if (C2 > CAP2) C2 = CAP2;
    int P = 2; while (P < C2) P <<= 1;
    for (int i = C2 + tid; i < P; i += THREADS) cand2[i] = 0u;  // pad = smallest
    __syncthreads();
    for (int kk = 2; kk <= P; kk <<= 1) {
        for (int j = kk >> 1; j > 0; j >>= 1) {
            for (int i = tid; i < P; i += THREADS) {
                int ixj = i ^ j;
                if (ixj > i) {
                    unsigned a = cand2[i], c2 = cand2[ixj];
                    bool sw = ((i & kk) == 0) ? (a < c2) : (a > c2); // descending
                    if (sw) { cand2[i] = c2; cand2[ixj] = a; }
                }
            }
            __syncthreads();
        }
    }

    // ---------- top-r boundary candidates + final per-row loss ---------------
    const int r = s_r;
    float csum = 0.0f;
    for (int i = tid; i < r; i += THREADS)
        csum += expf(TEMP * (key2f(cand2[i]) - m));

    float tot = lsum + csum;
    for (int off = 32; off > 0; off >>= 1) tot += __shfl_down(tot, off);
    if ((tid & 63) == 0) s_red[tid >> 6] = tot;
    __syncthreads();
    if (tid == 0) {
        float sum656 = 0.0f;
        #pragma unroll
        for (int w = 0; w < THREADS / 64; ++w) sum656 += s_red[w];
        float v656 = key2f(cand2[r - 1]);   // 656-th largest value in the row
        float t = s_t;
        float ps;
        if (t >= v656) {
            // target inside top-656 (or tied): candidate multiset == top-656
            ps = TEMP * m + logf(sum656) - TEMP * t;
        } else {
            // candidate multiset == top-655 + {t}
            ps = TEMP * m + logf(sum656 - expf(TEMP * (v656 - m)) + expf(TEMP * (t - m)))
                 - TEMP * t;
        }
        row_loss[row] = ps;
    }
}

__global__ __launch_bounds__(512)
void mmcl_reduce_kernel(const float* __restrict__ row_loss, float* __restrict__ out) {
    __shared__ float s_red[8];
    int tid = threadIdx.x;
    float v = row_loss[tid];
    for (int off = 32; off > 0; off >>= 1) v += __shfl_down(v, off);
    if ((tid & 63) == 0) s_red[tid >> 6] = v;
    __syncthreads();
    if (tid == 0) {
        float s = 0.0f;
        #pragma unroll
        for (int w = 0; w < 8; ++w) s += s_red[w];
        out[0] = s / 512.0f;
    }
}

extern "C" void kernel_launch(void* const* d_in, const int* in_sizes, int n_in,
                              void* d_out, int out_size, void* d_ws, size_t ws_size,
                              hipStream_t stream) {
    const float* logits = (const float*)d_in[0];   // [512, 65536] f32
    const int* targets = (const int*)d_in[1];      // [512] i32
    float* out = (float*)d_out;                    // scalar f32
    float* ws = (float*)d_ws;                      // >= 512 floats

    mmcl_row_kernel<<<512, THREADS, 0, stream>>>(logits, targets, ws);
    mmcl_reduce_kernel<<<1, 512, 0, stream>>>(ws, out);
}